// Round 11
// baseline (132.147 us; speedup 1.0000x reference)
//
#include <hip/hip_runtime.h>

#define NND 8192
#define KNBR 8
#define DD 128
#define EPSF 1e-5f
#define TSH 16384      // shorts per 128x128 bf16 tile (32 KB)

typedef __attribute__((ext_vector_type(8))) short bf16x8;
typedef __attribute__((ext_vector_type(4))) float f32x4;

__device__ __forceinline__ unsigned short f2bf(float f) {
    unsigned u = __float_as_uint(f);
    u += 0x7FFF + ((u >> 16) & 1);   // round-to-nearest-even
    return (unsigned short)(u >> 16);
}

__device__ __forceinline__ float bf_lo(unsigned u) { return __uint_as_float(u << 16); }
__device__ __forceinline__ float bf_hi(unsigned u) { return __uint_as_float(u & 0xFFFF0000u); }
__device__ __forceinline__ float bfs(unsigned short u) {
    return __uint_as_float((unsigned)u << 16);
}

__device__ __forceinline__ bf16x8 cvt8(const float* __restrict__ p) {
    float4 lo = *(const float4*)p;
    float4 hi = *(const float4*)(p + 4);
    bf16x8 r;
    r[0] = f2bf(lo.x); r[1] = f2bf(lo.y); r[2] = f2bf(lo.z); r[3] = f2bf(lo.w);
    r[4] = f2bf(hi.x); r[5] = f2bf(hi.y); r[6] = f2bf(hi.z); r[7] = f2bf(hi.w);
    return r;
}

// ---- async weight staging from pre-swizzled wbuf (linear DMA) ----
__device__ __forceinline__ void gload_lds16(const unsigned short* g, unsigned short* l) {
    __builtin_amdgcn_global_load_lds(
        (const __attribute__((address_space(1))) unsigned int*)(g),
        (__attribute__((address_space(3))) unsigned int*)(l), 16, 0, 0);
}

__device__ __forceinline__ void stage1(unsigned short* sh, const unsigned short* wb, int tid) {
    int lane = tid & 63, w = tid >> 6;
#pragma unroll
    for (int r = 0; r < 8; ++r) {
        int blk = (r * 4 + w) * 512;          // shorts, wave-uniform
        gload_lds16(wb + blk + lane * 8, sh + blk);
    }
}

// ---- in-kernel fp32->bf16 swizzled staging (mega's own 3 tiles) ----
// Logical 16B-chunk ch of row r stored at physical chunk ch^(r&7).
__device__ __forceinline__ void stage_cvt_sw(unsigned short* sh, const float* __restrict__ W,
                                             int wstr, int tid) {
    int r = tid >> 1, h = tid & 1;
    const float* src = W + (size_t)r * wstr;
#pragma unroll
    for (int i = 0; i < 8; ++i) {
        int ch = h * 8 + i;
        *(bf16x8*)(sh + r * 128 + ((ch ^ (r & 7)) << 3)) = cvt8(src + ch * 8);
    }
}

// ---- fragment loaders ----
__device__ __forceinline__ void load_af(bf16x8* af, const unsigned short* __restrict__ A,
                                        int rowBase, int lane) {
    int idx = lane & 15, q = lane >> 4;
    const unsigned short* Ar = A + (size_t)(rowBase + idx) * DD;
#pragma unroll
    for (int s = 0; s < 4; ++s) af[s] = *(const bf16x8*)(Ar + s * 32 + q * 8);
}

__device__ __forceinline__ void load_af_f32(bf16x8* af, const float* __restrict__ A,
                                            int rowBase, int lane) {
    int idx = lane & 15, q = lane >> 4;
    const float* Ar = A + (size_t)(rowBase + idx) * DD;
#pragma unroll
    for (int s = 0; s < 4; ++s) af[s] = cvt8(Ar + s * 32 + q * 8);
}

// ---- full-width MFMA over a swizzled LDS tile: 16 rows x 128 cols, K=128 ----
__device__ __forceinline__ void mma_sw(const bf16x8* af, const unsigned short* shB,
                                       int lane, f32x4* acc) {
    int idx = lane & 15, q = lane >> 4, k7 = idx & 7;
#pragma unroll
    for (int s = 0; s < 4; ++s)
#pragma unroll
        for (int ct = 0; ct < 8; ++ct) {
            int ch = (4 * s + q) ^ k7;
            bf16x8 bf = *(const bf16x8*)(shB + (ct * 16 + idx) * 128 + ch * 8);
            acc[ct] = __builtin_amdgcn_mfma_f32_16x16x32_bf16(af[s], bf, acc[ct], 0, 0, 0);
        }
}

// bf16-only store; optional relu
__device__ __forceinline__ void store_fw_b16(unsigned short* __restrict__ out,
        int rowBase, int lane, const f32x4* acc, const float* __restrict__ bias, bool relu) {
    int idx = lane & 15, q = lane >> 4;
#pragma unroll
    for (int ct = 0; ct < 8; ++ct) {
        float b = bias[ct * 16 + idx];
#pragma unroll
        for (int r = 0; r < 4; ++r) {
            float v = acc[ct][r] + b;
            if (relu) v = fmaxf(v, 0.f);
            out[(size_t)(rowBase + q * 4 + r) * DD + ct * 16 + idx] = f2bf(v);
        }
    }
}

// Fused epilogue, bf16 resid: v = relu(acc+bias) + bf(residB); out = LN(v)*g + b.
// Writes fp32 (if outF) and/or bf16 (if outB).
__device__ __forceinline__ void lnstore_fw_br(float* __restrict__ outF, int ostride, int oOff,
        const unsigned short* __restrict__ residB, int rowBase, int lane, f32x4* acc,
        const float* __restrict__ bias, const float* __restrict__ g,
        const float* __restrict__ bv, unsigned short* __restrict__ outB) {
    int idx = lane & 15, q = lane >> 4;
    float rsum[4] = {0.f, 0.f, 0.f, 0.f};
#pragma unroll
    for (int ct = 0; ct < 8; ++ct) {
        float b = bias[ct * 16 + idx];
#pragma unroll
        for (int r = 0; r < 4; ++r) {
            float t = fmaxf(acc[ct][r] + b, 0.f)
                    + bfs(residB[(size_t)(rowBase + q * 4 + r) * DD + ct * 16 + idx]);
            acc[ct][r] = t;
            rsum[r] += t;
        }
    }
#pragma unroll
    for (int r = 0; r < 4; ++r)
#pragma unroll
        for (int m = 1; m < 16; m <<= 1) rsum[r] += __shfl_xor(rsum[r], m, 64);
    float mu[4];
#pragma unroll
    for (int r = 0; r < 4; ++r) mu[r] = rsum[r] * (1.f / 128.f);
    float var[4] = {0.f, 0.f, 0.f, 0.f};
#pragma unroll
    for (int ct = 0; ct < 8; ++ct)
#pragma unroll
        for (int r = 0; r < 4; ++r) {
            float d = acc[ct][r] - mu[r];
            var[r] += d * d;
        }
#pragma unroll
    for (int r = 0; r < 4; ++r)
#pragma unroll
        for (int m = 1; m < 16; m <<= 1) var[r] += __shfl_xor(var[r], m, 64);
    float rs[4];
#pragma unroll
    for (int r = 0; r < 4; ++r) rs[r] = rsqrtf(var[r] * (1.f / 128.f) + EPSF);
#pragma unroll
    for (int ct = 0; ct < 8; ++ct) {
        float gg = g[ct * 16 + idx], bb = bv[ct * 16 + idx];
#pragma unroll
        for (int r = 0; r < 4; ++r) {
            float o = (acc[ct][r] - mu[r]) * rs[r] * gg + bb;
            size_t row = (size_t)(rowBase + q * 4 + r);
            if (outF) outF[row * ostride + oOff + ct * 16 + idx] = o;
            if (outB) outB[row * DD + ct * 16 + idx] = f2bf(o);
        }
    }
}

// ---- row-wise helpers ----
__device__ __forceinline__ float wave_sum(float s) {
#pragma unroll
    for (int m = 1; m < 64; m <<= 1) s += __shfl_xor(s, m, 64);
    return s;
}

// prop+LN with bf16 gathers and bf16 resid; writes fp32 (if outF) and/or bf16.
__device__ __forceinline__ void prop_ln_row_b(int row, int lane,
        const unsigned short* __restrict__ nxtB, const unsigned short* __restrict__ residB,
        const float* __restrict__ dinv, const int* __restrict__ kept,
        const int* __restrict__ neigh,
        const float* __restrict__ g, const float* __restrict__ b,
        float* __restrict__ outF, int oStride, int oOff,
        unsigned short* __restrict__ outB) {
    const unsigned* nxt2 = (const unsigned*)nxtB;
    float di = dinv[row];
    int km = kept[row];
    int idxs[KNBR]; float wj[KNBR];
#pragma unroll
    for (int j = 0; j < KNBR; ++j) {
        int nb = neigh[row * KNBR + j];
        bool k = (km >> j) & 1;
        idxs[j] = k ? nb : row;
        wj[j] = k ? dinv[nb] : 0.f;
    }
    unsigned vv[KNBR];
#pragma unroll
    for (int j = 0; j < KNBR; ++j) vv[j] = nxt2[(size_t)idxs[j] * 64 + lane];
    unsigned su = nxt2[(size_t)row * 64 + lane];
    float ax = di * bf_lo(su), ay = di * bf_hi(su);
#pragma unroll
    for (int j = 0; j < KNBR; ++j) {
        ax = fmaf(wj[j], bf_lo(vv[j]), ax);
        ay = fmaf(wj[j], bf_hi(vv[j]), ay);
    }
    unsigned ru = ((const unsigned*)residB)[(size_t)row * 64 + lane];
    float vx = fmaxf(di * ax, 0.f) + bf_lo(ru);
    float vy = fmaxf(di * ay, 0.f) + bf_hi(ru);
    float mu = wave_sum(vx + vy) * (1.f / 128.f);
    float dx = vx - mu, dy = vy - mu;
    float var = wave_sum(dx * dx + dy * dy) * (1.f / 128.f);
    float rs = rsqrtf(var + EPSF);
    float2 gg = ((const float2*)g)[lane];
    float2 bb = ((const float2*)b)[lane];
    float ox = dx * rs * gg.x + bb.x;
    float oy = dy * rs * gg.y + bb.y;
    if (outF) {
        float2 o; o.x = ox; o.y = oy;
        *reinterpret_cast<float2*>(outF + (size_t)row * oStride + oOff + lane * 2) = o;
    }
    if (outB) {
        unsigned pk = (unsigned)f2bf(ox) | ((unsigned)f2bf(oy) << 16);
        *(unsigned*)(outB + (size_t)row * DD + lane * 2) = pk;
    }
}

__device__ __forceinline__ void pool_row_b(int row, int lane,
        const unsigned short* __restrict__ enc, const int* __restrict__ neigh,
        const int* __restrict__ cnt, unsigned short* __restrict__ P) {
    int c = cnt[row];
    const unsigned* e32 = (const unsigned*)enc;
    unsigned vv[KNBR];
#pragma unroll
    for (int j = 0; j < KNBR; ++j) {
        int nb = neigh[row * KNBR + j];
        int src = (j < c) ? nb : row;
        vv[j] = e32[(size_t)src * 64 + lane];
    }
    float ax = -1e30f, ay = -1e30f;
#pragma unroll
    for (int j = 0; j < KNBR; ++j) {
        if (j < c) {
            ax = fmaxf(ax, bf_lo(vv[j]));
            ay = fmaxf(ay, bf_hi(vv[j]));
        }
    }
    unsigned o = 0u;
    if (c > 0)
        o = (__float_as_uint(ax) >> 16) | (__float_as_uint(ay) & 0xFFFF0000u);
    ((unsigned*)P)[(size_t)row * 64 + lane] = o;
}

// ---------------------------------------------------------------------------
// K1 mega_all: grid(472). K0 folded in — its outputs are first consumed at K2+.
//   bid<384 : GEMM from fp32 x, B converted in-LDS (swizzled).
//             grp0: G0b (no relu); grp1: E1b (relu); grp2: S1pb (no relu)
//   384..415: degree/dedupe
//   416..471: fp32->bf16 pre-swizzled wbuf tiles {1,2,5,6,7,8,9}
// ---------------------------------------------------------------------------
__global__ __launch_bounds__(256)
void mega_all(const float* __restrict__ x,
              const float* __restrict__ gcnW, const float* __restrict__ poolW,
              const float* __restrict__ mW,
              const float* __restrict__ gB0, const float* __restrict__ pB,
              const float* __restrict__ mB0,
              const int* __restrict__ neigh, const int* __restrict__ cnt,
              float* __restrict__ dinv, int* __restrict__ kept,
              unsigned short* __restrict__ wbuf,
              unsigned short* __restrict__ Gb, unsigned short* __restrict__ E1b,
              unsigned short* __restrict__ S1pb) {
    __shared__ __align__(16) unsigned short shB[TSH];
    const int bid = blockIdx.x, tid = threadIdx.x;
    const int lane = tid & 63, w = tid >> 6;

    if (bid < 384) {
        int grp = bid >> 7, bx = bid & 127;
        const float* W; int str;
        if (grp == 0)      { W = gcnW;  str = 128; }
        else if (grp == 1) { W = poolW; str = 128; }
        else               { W = mW;    str = 256; }
        stage_cvt_sw(shB, W, str, tid);
        int rowBase = (bx * 4 + w) * 16;
        bf16x8 af[4];
        load_af_f32(af, x, rowBase, lane);
        __syncthreads();
        f32x4 acc[8];
#pragma unroll
        for (int i = 0; i < 8; ++i) acc[i] = (f32x4){0.f, 0.f, 0.f, 0.f};
        mma_sw(af, shB, lane, acc);
        if (grp == 0)      store_fw_b16(Gb, rowBase, lane, acc, gB0, false);
        else if (grp == 1) store_fw_b16(E1b, rowBase, lane, acc, pB, true);
        else               store_fw_b16(S1pb, rowBase, lane, acc, mB0, false);
    } else if (bid < 416) {
        int i = (bid - 384) * 256 + tid;
        int c = cnt[i];
        int nb[KNBR];
#pragma unroll
        for (int j = 0; j < KNBR; ++j) nb[j] = neigh[i * KNBR + j];
        int mask = 0, deg = 1;
#pragma unroll
        for (int j = 0; j < KNBR; ++j) {
            if (j < c) {
                int v = nb[j];
                bool dup = (v == i);
                for (int jj = 0; jj < j; ++jj)
                    if (nb[jj] == v) { dup = true; }
                if (!dup) { mask |= (1 << j); deg++; }
            }
        }
        dinv[i] = rsqrtf((float)deg);
        kept[i] = mask;
    } else {
        int cid = (bid - 416) * 256 + tid;    // 0..14335
        int u = cid >> 11, c2 = cid & 2047, row = c2 >> 4, ch = c2 & 15;
        const float* base; int str; int t;
        if (u == 0)      { t = 1; base = gcnW + 16384;       str = 128; }
        else if (u == 1) { t = 2; base = gcnW + 32768;       str = 128; }
        else if (u == 2) { t = 5; base = mW + 128;           str = 256; }
        else if (u == 3) { t = 6; base = mW + 32768;         str = 256; }
        else if (u == 4) { t = 7; base = mW + 32768 + 128;   str = 256; }
        else if (u == 5) { t = 8; base = mW + 65536;         str = 256; }
        else             { t = 9; base = mW + 65536 + 128;   str = 256; }
        bf16x8 v = cvt8(base + (size_t)row * str + ch * 8);
        *(bf16x8*)(wbuf + t * TSH + row * 128 + ((ch ^ (row & 7)) << 3)) = v;
    }
}

// prop_pool: grid(2048). 1 prop row + 1 pool row per wave (bf16 throughout).
__global__ __launch_bounds__(256)
void prop_pool(const unsigned short* __restrict__ nxtB,
               const unsigned short* __restrict__ residB,
               const float* __restrict__ dinv, const int* __restrict__ kept,
               const int* __restrict__ neigh, const int* __restrict__ cnt,
               const float* __restrict__ g, const float* __restrict__ b,
               float* __restrict__ outF, int oStride,
               unsigned short* __restrict__ outB,
               const unsigned short* __restrict__ enc,
               unsigned short* __restrict__ P) {
    int row = blockIdx.x * 4 + (threadIdx.x >> 6);
    int lane = threadIdx.x & 63;
    prop_ln_row_b(row, lane, nxtB, residB, dinv, kept, neigh, g, b,
                  outF, oStride, 0, outB);
    pool_row_b(row, lane, enc, neigh, cnt, P);
}

// step4: grid (128, 2). y0: S1b = bf16(relu(S1pb + Pb@mW0R^T))
//                       y1: G1b = bf16(H1b@gcnW1^T + gB1)
__global__ __launch_bounds__(256)
void gemm_step4(const unsigned short* __restrict__ Pb, const unsigned short* __restrict__ H1b,
                const unsigned short* __restrict__ wbuf, const float* __restrict__ gB1,
                const unsigned short* __restrict__ S1pb, unsigned short* __restrict__ S1b,
                unsigned short* __restrict__ Gb) {
    __shared__ __align__(16) unsigned short shB[TSH];
    const int tid = threadIdx.x, lane = tid & 63, w = tid >> 6;
    const int rowBase = ((int)blockIdx.x * 4 + w) * 16;
    f32x4 acc[8];
#pragma unroll
    for (int i = 0; i < 8; ++i) acc[i] = (f32x4){0.f, 0.f, 0.f, 0.f};
    bf16x8 af[4];
    if (blockIdx.y == 0) {
        stage1(shB, wbuf + 5 * TSH, tid);   // mW0R
        load_af(af, Pb, rowBase, lane);
        __syncthreads();
        mma_sw(af, shB, lane, acc);
        int idx = lane & 15, q = lane >> 4;
#pragma unroll
        for (int ct = 0; ct < 8; ++ct)
#pragma unroll
            for (int r = 0; r < 4; ++r) {
                size_t o = (size_t)(rowBase + q * 4 + r) * DD + ct * 16 + idx;
                float v = fmaxf(bfs(S1pb[o]) + acc[ct][r], 0.f);
                S1b[o] = f2bf(v);
            }
    } else {
        stage1(shB, wbuf + 1 * TSH, tid);   // gcnW1
        load_af(af, H1b, rowBase, lane);
        __syncthreads();
        mma_sw(af, shB, lane, acc);
        store_fw_b16(Gb, rowBase, lane, acc, gB1, false);
    }
}

// step6: grid (128, 2).
//  y0: S2b = bf16(LN(relu([S1b|Pb]@mW1^T + mB1) + S1b))
//  y1: G2b = bf16(H2b@gcnW2^T + gB2)
__global__ __launch_bounds__(256)
void gemm_step6(const unsigned short* __restrict__ S1b, const unsigned short* __restrict__ Pb,
                const unsigned short* __restrict__ H2b,
                const unsigned short* __restrict__ wbuf,
                const float* __restrict__ mB1, const float* __restrict__ gB2,
                const float* __restrict__ sg, const float* __restrict__ sb,
                unsigned short* __restrict__ S2b, unsigned short* __restrict__ Gb) {
    __shared__ __align__(16) unsigned short shB[2 * TSH];
    const int tid = threadIdx.x, lane = tid & 63, w = tid >> 6;
    const int rowBase = ((int)blockIdx.x * 4 + w) * 16;
    f32x4 acc[8];
#pragma unroll
    for (int i = 0; i < 8; ++i) acc[i] = (f32x4){0.f, 0.f, 0.f, 0.f};
    if (blockIdx.y == 0) {
        stage1(shB, wbuf + 6 * TSH, tid);        // mW1L
        stage1(shB + TSH, wbuf + 7 * TSH, tid);  // mW1R
        bf16x8 af1[4], af2[4];
        load_af(af1, S1b, rowBase, lane);
        load_af(af2, Pb, rowBase, lane);
        __syncthreads();
        mma_sw(af1, shB, lane, acc);
        mma_sw(af2, shB + TSH, lane, acc);
        lnstore_fw_br(nullptr, DD, 0, S1b, rowBase, lane, acc, mB1, sg, sb, S2b);
    } else {
        stage1(shB, wbuf + 2 * TSH, tid);        // gcnW2
        bf16x8 af[4];
        load_af(af, H2b, rowBase, lane);
        __syncthreads();
        mma_sw(af, shB, lane, acc);
        store_fw_b16(Gb, rowBase, lane, acc, gB2, false);
    }
}

// final: grid (128). out[:, D:] = LN(relu([S2b|Pb]@mW2^T + mB2) + S2b)
__global__ __launch_bounds__(256)
void gemm_final(const unsigned short* __restrict__ S2b, const unsigned short* __restrict__ Pb,
                const unsigned short* __restrict__ wbuf,
                const float* __restrict__ mB2,
                const float* __restrict__ sg2, const float* __restrict__ sb2,
                float* __restrict__ out) {
    __shared__ __align__(16) unsigned short shB[2 * TSH];
    const int tid = threadIdx.x, lane = tid & 63, w = tid >> 6;
    const int rowBase = ((int)blockIdx.x * 4 + w) * 16;
    f32x4 acc[8];
#pragma unroll
    for (int i = 0; i < 8; ++i) acc[i] = (f32x4){0.f, 0.f, 0.f, 0.f};
    stage1(shB, wbuf + 8 * TSH, tid);        // mW2L
    stage1(shB + TSH, wbuf + 9 * TSH, tid);  // mW2R
    bf16x8 af1[4], af2[4];
    load_af(af1, S2b, rowBase, lane);
    load_af(af2, Pb, rowBase, lane);
    __syncthreads();
    mma_sw(af1, shB, lane, acc);
    mma_sw(af2, shB + TSH, lane, acc);
    lnstore_fw_br(out, 2 * DD, DD, S2b, rowBase, lane, acc, mB2, sg2, sb2, nullptr);
}

extern "C" void kernel_launch(void* const* d_in, const int* in_sizes, int n_in,
                              void* d_out, int out_size, void* d_ws, size_t ws_size,
                              hipStream_t stream) {
    (void)in_sizes; (void)n_in; (void)out_size; (void)ws_size;
    const float* x      = (const float*)d_in[0];
    const int*   neigh  = (const int*)d_in[1];
    const int*   cnt    = (const int*)d_in[2];
    const float* gcnW   = (const float*)d_in[3];
    const float* gcnB   = (const float*)d_in[4];
    const float* gcnG   = (const float*)d_in[5];
    const float* gcnBb  = (const float*)d_in[6];
    const float* poolW  = (const float*)d_in[7];
    const float* poolB  = (const float*)d_in[8];
    const float* mW     = (const float*)d_in[9];
    const float* mB     = (const float*)d_in[10];
    const float* sg     = (const float*)d_in[11];
    const float* sb     = (const float*)d_in[12];
    float* out = (float*)d_out;

    char* ws = (char*)d_ws;
    float* dinv = (float*)ws;                                 // 32 KB
    int*   kept = (int*)(ws + 32 * 1024);                     // 32 KB
    unsigned short* wbuf = (unsigned short*)(ws + 64 * 1024); // 320 KB (10 tiles)
    unsigned short* Gb   = (unsigned short*)(ws + 448 * 1024);// bf16: 2 MB each
    unsigned short* E1b  = Gb   + NND * DD;
    unsigned short* S1pb = E1b  + NND * DD;
    unsigned short* Pb   = S1pb + NND * DD;
    unsigned short* H1b  = Pb   + NND * DD;
    unsigned short* H2b  = H1b  + NND * DD;
    unsigned short* S1b  = H2b  + NND * DD;
    unsigned short* S2b  = S1b  + NND * DD;

    dim3 blk(256);
    dim3 rgrid(NND / 4);

    // K1: [G0b | E1b | S1pb] from x + degree/dedupe + wbuf tiles {1,2,5..9}
    mega_all<<<dim3(472), blk, 0, stream>>>(x, gcnW, poolW, mW, gcnB, poolB, mB,
                                            neigh, cnt, dinv, kept, wbuf,
                                            Gb, E1b, S1pb);
    // K2: H1b = propLN(G0b, resid=G0b); P1b = pool(E1b)
    prop_pool<<<rgrid, blk, 0, stream>>>(Gb, Gb, dinv, kept, neigh, cnt,
                                         gcnG, gcnBb, nullptr, DD, H1b, E1b, Pb);
    // K3: S1b = relu(S1pb + P1b@mW0R^T); G1b = H1b@gcnW1^T + b1
    gemm_step4<<<dim3(128, 2), blk, 0, stream>>>(Pb, H1b, wbuf, gcnB + DD,
                                                 S1pb, S1b, Gb);
    // K4: H2b = propLN(G1b, resid=H1b); P2b = pool(S1b)
    prop_pool<<<rgrid, blk, 0, stream>>>(Gb, H1b, dinv, kept, neigh, cnt,
                                         gcnG + DD, gcnBb + DD, nullptr, DD,
                                         H2b, S1b, Pb);
    // K5: S2b = LN(relu([S1b|P2b]@mW1^T + mB1) + S1b); G2b = H2b@gcnW2^T + b2
    gemm_step6<<<dim3(128, 2), blk, 0, stream>>>(S1b, Pb, H2b, wbuf,
                                                 mB + DD, gcnB + 2 * DD, sg, sb,
                                                 S2b, Gb);
    // K6: outL = propLN(G2b, resid=H2b) -> fp32 out; P3b = pool(S2b)
    prop_pool<<<rgrid, blk, 0, stream>>>(Gb, H2b, dinv, kept, neigh, cnt,
                                         gcnG + 2 * DD, gcnBb + 2 * DD,
                                         out, 2 * DD, nullptr, S2b, Pb);
    // K7: outR = LN(relu([S2b|P3b]@mW2^T + mB2) + S2b)
    gemm_final<<<dim3(128), blk, 0, stream>>>(S2b, Pb, wbuf, mB + 2 * DD,
                                              sg + DD, sb + DD, out);
}

// Round 12
// 129.251 us; speedup vs baseline: 1.0224x; 1.0224x over previous
//
#include <hip/hip_runtime.h>

#define NND 8192
#define KNBR 8
#define DD 128
#define EPSF 1e-5f
#define TSH 16384      // shorts per 128x128 bf16 tile (32 KB)

typedef __attribute__((ext_vector_type(8))) short bf16x8;
typedef __attribute__((ext_vector_type(4))) float f32x4;

__device__ __forceinline__ unsigned short f2bf(float f) {
    unsigned u = __float_as_uint(f);
    u += 0x7FFF + ((u >> 16) & 1);   // round-to-nearest-even
    return (unsigned short)(u >> 16);
}

__device__ __forceinline__ float bf_lo(unsigned u) { return __uint_as_float(u << 16); }
__device__ __forceinline__ float bf_hi(unsigned u) { return __uint_as_float(u & 0xFFFF0000u); }
__device__ __forceinline__ float bfs(unsigned short u) {
    return __uint_as_float((unsigned)u << 16);
}

__device__ __forceinline__ bf16x8 cvt8(const float* __restrict__ p) {
    float4 lo = *(const float4*)p;
    float4 hi = *(const float4*)(p + 4);
    bf16x8 r;
    r[0] = f2bf(lo.x); r[1] = f2bf(lo.y); r[2] = f2bf(lo.z); r[3] = f2bf(lo.w);
    r[4] = f2bf(hi.x); r[5] = f2bf(hi.y); r[6] = f2bf(hi.z); r[7] = f2bf(hi.w);
    return r;
}

// ---- async weight staging from pre-swizzled wbuf (linear DMA) ----
__device__ __forceinline__ void gload_lds16(const unsigned short* g, unsigned short* l) {
    __builtin_amdgcn_global_load_lds(
        (const __attribute__((address_space(1))) unsigned int*)(g),
        (__attribute__((address_space(3))) unsigned int*)(l), 16, 0, 0);
}

__device__ __forceinline__ void stage1(unsigned short* sh, const unsigned short* wb, int tid) {
    int lane = tid & 63, w = tid >> 6;
#pragma unroll
    for (int r = 0; r < 8; ++r) {
        int blk = (r * 4 + w) * 512;          // shorts, wave-uniform
        gload_lds16(wb + blk + lane * 8, sh + blk);
    }
}

// ---- in-kernel fp32->bf16 swizzled staging (mega's own 3 tiles) ----
// Logical 16B-chunk ch of row r stored at physical chunk ch^(r&7).
__device__ __forceinline__ void stage_cvt_sw(unsigned short* sh, const float* __restrict__ W,
                                             int wstr, int tid) {
    int r = tid >> 1, h = tid & 1;
    const float* src = W + (size_t)r * wstr;
#pragma unroll
    for (int i = 0; i < 8; ++i) {
        int ch = h * 8 + i;
        *(bf16x8*)(sh + r * 128 + ((ch ^ (r & 7)) << 3)) = cvt8(src + ch * 8);
    }
}

// ---- fragment loaders ----
__device__ __forceinline__ void load_af(bf16x8* af, const unsigned short* __restrict__ A,
                                        int rowBase, int lane) {
    int idx = lane & 15, q = lane >> 4;
    const unsigned short* Ar = A + (size_t)(rowBase + idx) * DD;
#pragma unroll
    for (int s = 0; s < 4; ++s) af[s] = *(const bf16x8*)(Ar + s * 32 + q * 8);
}

__device__ __forceinline__ void load_af_f32(bf16x8* af, const float* __restrict__ A,
                                            int rowBase, int lane) {
    int idx = lane & 15, q = lane >> 4;
    const float* Ar = A + (size_t)(rowBase + idx) * DD;
#pragma unroll
    for (int s = 0; s < 4; ++s) af[s] = cvt8(Ar + s * 32 + q * 8);
}

// ---- full-width MFMA over a swizzled LDS tile: 16 rows x 128 cols, K=128 ----
__device__ __forceinline__ void mma_sw(const bf16x8* af, const unsigned short* shB,
                                       int lane, f32x4* acc) {
    int idx = lane & 15, q = lane >> 4, k7 = idx & 7;
#pragma unroll
    for (int s = 0; s < 4; ++s)
#pragma unroll
        for (int ct = 0; ct < 8; ++ct) {
            int ch = (4 * s + q) ^ k7;
            bf16x8 bf = *(const bf16x8*)(shB + (ct * 16 + idx) * 128 + ch * 8);
            acc[ct] = __builtin_amdgcn_mfma_f32_16x16x32_bf16(af[s], bf, acc[ct], 0, 0, 0);
        }
}

// bf16-only store; optional relu
__device__ __forceinline__ void store_fw_b16(unsigned short* __restrict__ out,
        int rowBase, int lane, const f32x4* acc, const float* __restrict__ bias, bool relu) {
    int idx = lane & 15, q = lane >> 4;
#pragma unroll
    for (int ct = 0; ct < 8; ++ct) {
        float b = bias[ct * 16 + idx];
#pragma unroll
        for (int r = 0; r < 4; ++r) {
            float v = acc[ct][r] + b;
            if (relu) v = fmaxf(v, 0.f);
            out[(size_t)(rowBase + q * 4 + r) * DD + ct * 16 + idx] = f2bf(v);
        }
    }
}

// Fused epilogue, bf16 resid: v = relu(acc+bias) + bf(residB); out = LN(v)*g + b.
// Writes fp32 (if outF) and/or bf16 (if outB).
__device__ __forceinline__ void lnstore_fw_br(float* __restrict__ outF, int ostride, int oOff,
        const unsigned short* __restrict__ residB, int rowBase, int lane, f32x4* acc,
        const float* __restrict__ bias, const float* __restrict__ g,
        const float* __restrict__ bv, unsigned short* __restrict__ outB) {
    int idx = lane & 15, q = lane >> 4;
    float rsum[4] = {0.f, 0.f, 0.f, 0.f};
#pragma unroll
    for (int ct = 0; ct < 8; ++ct) {
        float b = bias[ct * 16 + idx];
#pragma unroll
        for (int r = 0; r < 4; ++r) {
            float t = fmaxf(acc[ct][r] + b, 0.f)
                    + bfs(residB[(size_t)(rowBase + q * 4 + r) * DD + ct * 16 + idx]);
            acc[ct][r] = t;
            rsum[r] += t;
        }
    }
#pragma unroll
    for (int r = 0; r < 4; ++r)
#pragma unroll
        for (int m = 1; m < 16; m <<= 1) rsum[r] += __shfl_xor(rsum[r], m, 64);
    float mu[4];
#pragma unroll
    for (int r = 0; r < 4; ++r) mu[r] = rsum[r] * (1.f / 128.f);
    float var[4] = {0.f, 0.f, 0.f, 0.f};
#pragma unroll
    for (int ct = 0; ct < 8; ++ct)
#pragma unroll
        for (int r = 0; r < 4; ++r) {
            float d = acc[ct][r] - mu[r];
            var[r] += d * d;
        }
#pragma unroll
    for (int r = 0; r < 4; ++r)
#pragma unroll
        for (int m = 1; m < 16; m <<= 1) var[r] += __shfl_xor(var[r], m, 64);
    float rs[4];
#pragma unroll
    for (int r = 0; r < 4; ++r) rs[r] = rsqrtf(var[r] * (1.f / 128.f) + EPSF);
#pragma unroll
    for (int ct = 0; ct < 8; ++ct) {
        float gg = g[ct * 16 + idx], bb = bv[ct * 16 + idx];
#pragma unroll
        for (int r = 0; r < 4; ++r) {
            float o = (acc[ct][r] - mu[r]) * rs[r] * gg + bb;
            size_t row = (size_t)(rowBase + q * 4 + r);
            if (outF) outF[row * ostride + oOff + ct * 16 + idx] = o;
            if (outB) outB[row * DD + ct * 16 + idx] = f2bf(o);
        }
    }
}

// ---- row-wise helpers ----
__device__ __forceinline__ float wave_sum(float s) {
#pragma unroll
    for (int m = 1; m < 64; m <<= 1) s += __shfl_xor(s, m, 64);
    return s;
}

// Merged prop+pool for one row: metadata loaded ONCE, all 17 gathers issued
// back-to-back before any math (max memory-level parallelism per wave).
// Arithmetic is identical (same order) to the previous split functions.
__device__ __forceinline__ void prop_pool_row(int row, int lane,
        const unsigned short* __restrict__ nxtB, const unsigned short* __restrict__ residB,
        const unsigned short* __restrict__ enc,
        const float* __restrict__ dinv, const int* __restrict__ kept,
        const int* __restrict__ neigh, const int* __restrict__ cnt,
        const float* __restrict__ g, const float* __restrict__ b,
        float* __restrict__ outF, int oStride,
        unsigned short* __restrict__ outB, unsigned short* __restrict__ P) {
    const unsigned* nxt2 = (const unsigned*)nxtB;
    const unsigned* e32  = (const unsigned*)enc;
    // ---- one metadata read ----
    int nb[KNBR];
#pragma unroll
    for (int j = 0; j < KNBR; ++j) nb[j] = neigh[row * KNBR + j];
    int km = kept[row];
    int c  = cnt[row];
    float di = dinv[row];
    // ---- all gather addresses, then all 17 gathers in flight ----
    int idxs[KNBR]; float wj[KNBR];
#pragma unroll
    for (int j = 0; j < KNBR; ++j) {
        bool k = (km >> j) & 1;
        idxs[j] = k ? nb[j] : row;
        wj[j] = k ? dinv[nb[j]] : 0.f;
    }
    unsigned vv[KNBR], pv[KNBR];
#pragma unroll
    for (int j = 0; j < KNBR; ++j) vv[j] = nxt2[(size_t)idxs[j] * 64 + lane];
#pragma unroll
    for (int j = 0; j < KNBR; ++j) {
        int src = (j < c) ? nb[j] : row;
        pv[j] = e32[(size_t)src * 64 + lane];
    }
    unsigned su = nxt2[(size_t)row * 64 + lane];
    unsigned ru = ((const unsigned*)residB)[(size_t)row * 64 + lane];
    // ---- prop math (unchanged order) ----
    float ax = di * bf_lo(su), ay = di * bf_hi(su);
#pragma unroll
    for (int j = 0; j < KNBR; ++j) {
        ax = fmaf(wj[j], bf_lo(vv[j]), ax);
        ay = fmaf(wj[j], bf_hi(vv[j]), ay);
    }
    float vx = fmaxf(di * ax, 0.f) + bf_lo(ru);
    float vy = fmaxf(di * ay, 0.f) + bf_hi(ru);
    float mu = wave_sum(vx + vy) * (1.f / 128.f);
    float dx = vx - mu, dy = vy - mu;
    float var = wave_sum(dx * dx + dy * dy) * (1.f / 128.f);
    float rs = rsqrtf(var + EPSF);
    float2 gg = ((const float2*)g)[lane];
    float2 bb = ((const float2*)b)[lane];
    float ox = dx * rs * gg.x + bb.x;
    float oy = dy * rs * gg.y + bb.y;
    if (outF) {
        float2 o; o.x = ox; o.y = oy;
        *reinterpret_cast<float2*>(outF + (size_t)row * oStride + lane * 2) = o;
    }
    if (outB) {
        unsigned pk = (unsigned)f2bf(ox) | ((unsigned)f2bf(oy) << 16);
        *(unsigned*)(outB + (size_t)row * DD + lane * 2) = pk;
    }
    // ---- pool math (unchanged order) ----
    float px = -1e30f, py = -1e30f;
#pragma unroll
    for (int j = 0; j < KNBR; ++j) {
        if (j < c) {
            px = fmaxf(px, bf_lo(pv[j]));
            py = fmaxf(py, bf_hi(pv[j]));
        }
    }
    unsigned o = 0u;
    if (c > 0)
        o = (__float_as_uint(px) >> 16) | (__float_as_uint(py) & 0xFFFF0000u);
    ((unsigned*)P)[(size_t)row * 64 + lane] = o;
}

// ---------------------------------------------------------------------------
// K1 mega_all: grid(472). Aux work (deg/dedupe, wbuf tiles) folded in —
// first consumed at K2+.
// ---------------------------------------------------------------------------
__global__ __launch_bounds__(256)
void mega_all(const float* __restrict__ x,
              const float* __restrict__ gcnW, const float* __restrict__ poolW,
              const float* __restrict__ mW,
              const float* __restrict__ gB0, const float* __restrict__ pB,
              const float* __restrict__ mB0,
              const int* __restrict__ neigh, const int* __restrict__ cnt,
              float* __restrict__ dinv, int* __restrict__ kept,
              unsigned short* __restrict__ wbuf,
              unsigned short* __restrict__ Gb, unsigned short* __restrict__ E1b,
              unsigned short* __restrict__ S1pb) {
    __shared__ __align__(16) unsigned short shB[TSH];
    const int bid = blockIdx.x, tid = threadIdx.x;
    const int lane = tid & 63, w = tid >> 6;

    if (bid < 384) {
        int grp = bid >> 7, bx = bid & 127;
        const float* W; int str;
        if (grp == 0)      { W = gcnW;  str = 128; }
        else if (grp == 1) { W = poolW; str = 128; }
        else               { W = mW;    str = 256; }
        stage_cvt_sw(shB, W, str, tid);
        int rowBase = (bx * 4 + w) * 16;
        bf16x8 af[4];
        load_af_f32(af, x, rowBase, lane);
        __syncthreads();
        f32x4 acc[8];
#pragma unroll
        for (int i = 0; i < 8; ++i) acc[i] = (f32x4){0.f, 0.f, 0.f, 0.f};
        mma_sw(af, shB, lane, acc);
        if (grp == 0)      store_fw_b16(Gb, rowBase, lane, acc, gB0, false);
        else if (grp == 1) store_fw_b16(E1b, rowBase, lane, acc, pB, true);
        else               store_fw_b16(S1pb, rowBase, lane, acc, mB0, false);
    } else if (bid < 416) {
        int i = (bid - 384) * 256 + tid;
        int c = cnt[i];
        int nb[KNBR];
#pragma unroll
        for (int j = 0; j < KNBR; ++j) nb[j] = neigh[i * KNBR + j];
        int mask = 0, deg = 1;
#pragma unroll
        for (int j = 0; j < KNBR; ++j) {
            if (j < c) {
                int v = nb[j];
                bool dup = (v == i);
                for (int jj = 0; jj < j; ++jj)
                    if (nb[jj] == v) { dup = true; }
                if (!dup) { mask |= (1 << j); deg++; }
            }
        }
        dinv[i] = rsqrtf((float)deg);
        kept[i] = mask;
    } else {
        int cid = (bid - 416) * 256 + tid;    // 0..14335
        int u = cid >> 11, c2 = cid & 2047, row = c2 >> 4, ch = c2 & 15;
        const float* base; int str; int t;
        if (u == 0)      { t = 1; base = gcnW + 16384;       str = 128; }
        else if (u == 1) { t = 2; base = gcnW + 32768;       str = 128; }
        else if (u == 2) { t = 5; base = mW + 128;           str = 256; }
        else if (u == 3) { t = 6; base = mW + 32768;         str = 256; }
        else if (u == 4) { t = 7; base = mW + 32768 + 128;   str = 256; }
        else if (u == 5) { t = 8; base = mW + 65536;         str = 256; }
        else             { t = 9; base = mW + 65536 + 128;   str = 256; }
        bf16x8 v = cvt8(base + (size_t)row * str + ch * 8);
        *(bf16x8*)(wbuf + t * TSH + row * 128 + ((ch ^ (row & 7)) << 3)) = v;
    }
}

// prop_pool: grid(2048). 1 merged prop+pool row per wave; 17 gathers in flight.
__global__ __launch_bounds__(256)
void prop_pool(const unsigned short* __restrict__ nxtB,
               const unsigned short* __restrict__ residB,
               const float* __restrict__ dinv, const int* __restrict__ kept,
               const int* __restrict__ neigh, const int* __restrict__ cnt,
               const float* __restrict__ g, const float* __restrict__ b,
               float* __restrict__ outF, int oStride,
               unsigned short* __restrict__ outB,
               const unsigned short* __restrict__ enc,
               unsigned short* __restrict__ P) {
    int row = blockIdx.x * 4 + (threadIdx.x >> 6);
    int lane = threadIdx.x & 63;
    prop_pool_row(row, lane, nxtB, residB, enc, dinv, kept, neigh, cnt,
                  g, b, outF, oStride, outB, P);
}

// step4: grid (128, 2). y0: S1b = bf16(relu(S1pb + Pb@mW0R^T))
//                       y1: G1b = bf16(H1b@gcnW1^T + gB1)
__global__ __launch_bounds__(256)
void gemm_step4(const unsigned short* __restrict__ Pb, const unsigned short* __restrict__ H1b,
                const unsigned short* __restrict__ wbuf, const float* __restrict__ gB1,
                const unsigned short* __restrict__ S1pb, unsigned short* __restrict__ S1b,
                unsigned short* __restrict__ Gb) {
    __shared__ __align__(16) unsigned short shB[TSH];
    const int tid = threadIdx.x, lane = tid & 63, w = tid >> 6;
    const int rowBase = ((int)blockIdx.x * 4 + w) * 16;
    f32x4 acc[8];
#pragma unroll
    for (int i = 0; i < 8; ++i) acc[i] = (f32x4){0.f, 0.f, 0.f, 0.f};
    bf16x8 af[4];
    if (blockIdx.y == 0) {
        stage1(shB, wbuf + 5 * TSH, tid);   // mW0R
        load_af(af, Pb, rowBase, lane);
        __syncthreads();
        mma_sw(af, shB, lane, acc);
        int idx = lane & 15, q = lane >> 4;
#pragma unroll
        for (int ct = 0; ct < 8; ++ct)
#pragma unroll
            for (int r = 0; r < 4; ++r) {
                size_t o = (size_t)(rowBase + q * 4 + r) * DD + ct * 16 + idx;
                float v = fmaxf(bfs(S1pb[o]) + acc[ct][r], 0.f);
                S1b[o] = f2bf(v);
            }
    } else {
        stage1(shB, wbuf + 1 * TSH, tid);   // gcnW1
        load_af(af, H1b, rowBase, lane);
        __syncthreads();
        mma_sw(af, shB, lane, acc);
        store_fw_b16(Gb, rowBase, lane, acc, gB1, false);
    }
}

// step6: grid (128, 2).
//  y0: S2b = bf16(LN(relu([S1b|Pb]@mW1^T + mB1) + S1b))
//  y1: G2b = bf16(H2b@gcnW2^T + gB2)
__global__ __launch_bounds__(256)
void gemm_step6(const unsigned short* __restrict__ S1b, const unsigned short* __restrict__ Pb,
                const unsigned short* __restrict__ H2b,
                const unsigned short* __restrict__ wbuf,
                const float* __restrict__ mB1, const float* __restrict__ gB2,
                const float* __restrict__ sg, const float* __restrict__ sb,
                unsigned short* __restrict__ S2b, unsigned short* __restrict__ Gb) {
    __shared__ __align__(16) unsigned short shB[2 * TSH];
    const int tid = threadIdx.x, lane = tid & 63, w = tid >> 6;
    const int rowBase = ((int)blockIdx.x * 4 + w) * 16;
    f32x4 acc[8];
#pragma unroll
    for (int i = 0; i < 8; ++i) acc[i] = (f32x4){0.f, 0.f, 0.f, 0.f};
    if (blockIdx.y == 0) {
        stage1(shB, wbuf + 6 * TSH, tid);        // mW1L
        stage1(shB + TSH, wbuf + 7 * TSH, tid);  // mW1R
        bf16x8 af1[4], af2[4];
        load_af(af1, S1b, rowBase, lane);
        load_af(af2, Pb, rowBase, lane);
        __syncthreads();
        mma_sw(af1, shB, lane, acc);
        mma_sw(af2, shB + TSH, lane, acc);
        lnstore_fw_br(nullptr, DD, 0, S1b, rowBase, lane, acc, mB1, sg, sb, S2b);
    } else {
        stage1(shB, wbuf + 2 * TSH, tid);        // gcnW2
        bf16x8 af[4];
        load_af(af, H2b, rowBase, lane);
        __syncthreads();
        mma_sw(af, shB, lane, acc);
        store_fw_b16(Gb, rowBase, lane, acc, gB2, false);
    }
}

// final: grid (128). out[:, D:] = LN(relu([S2b|Pb]@mW2^T + mB2) + S2b)
__global__ __launch_bounds__(256)
void gemm_final(const unsigned short* __restrict__ S2b, const unsigned short* __restrict__ Pb,
                const unsigned short* __restrict__ wbuf,
                const float* __restrict__ mB2,
                const float* __restrict__ sg2, const float* __restrict__ sb2,
                float* __restrict__ out) {
    __shared__ __align__(16) unsigned short shB[2 * TSH];
    const int tid = threadIdx.x, lane = tid & 63, w = tid >> 6;
    const int rowBase = ((int)blockIdx.x * 4 + w) * 16;
    f32x4 acc[8];
#pragma unroll
    for (int i = 0; i < 8; ++i) acc[i] = (f32x4){0.f, 0.f, 0.f, 0.f};
    stage1(shB, wbuf + 8 * TSH, tid);        // mW2L
    stage1(shB + TSH, wbuf + 9 * TSH, tid);  // mW2R
    bf16x8 af1[4], af2[4];
    load_af(af1, S2b, rowBase, lane);
    load_af(af2, Pb, rowBase, lane);
    __syncthreads();
    mma_sw(af1, shB, lane, acc);
    mma_sw(af2, shB + TSH, lane, acc);
    lnstore_fw_br(out, 2 * DD, DD, S2b, rowBase, lane, acc, mB2, sg2, sb2, nullptr);
}

extern "C" void kernel_launch(void* const* d_in, const int* in_sizes, int n_in,
                              void* d_out, int out_size, void* d_ws, size_t ws_size,
                              hipStream_t stream) {
    (void)in_sizes; (void)n_in; (void)out_size; (void)ws_size;
    const float* x      = (const float*)d_in[0];
    const int*   neigh  = (const int*)d_in[1];
    const int*   cnt    = (const int*)d_in[2];
    const float* gcnW   = (const float*)d_in[3];
    const float* gcnB   = (const float*)d_in[4];
    const float* gcnG   = (const float*)d_in[5];
    const float* gcnBb  = (const float*)d_in[6];
    const float* poolW  = (const float*)d_in[7];
    const float* poolB  = (const float*)d_in[8];
    const float* mW     = (const float*)d_in[9];
    const float* mB     = (const float*)d_in[10];
    const float* sg     = (const float*)d_in[11];
    const float* sb     = (const float*)d_in[12];
    float* out = (float*)d_out;

    char* ws = (char*)d_ws;
    float* dinv = (float*)ws;                                 // 32 KB
    int*   kept = (int*)(ws + 32 * 1024);                     // 32 KB
    unsigned short* wbuf = (unsigned short*)(ws + 64 * 1024); // 320 KB (10 tiles)
    unsigned short* Gb   = (unsigned short*)(ws + 448 * 1024);// bf16: 2 MB each
    unsigned short* E1b  = Gb   + NND * DD;
    unsigned short* S1pb = E1b  + NND * DD;
    unsigned short* Pb   = S1pb + NND * DD;
    unsigned short* H1b  = Pb   + NND * DD;
    unsigned short* H2b  = H1b  + NND * DD;
    unsigned short* S1b  = H2b  + NND * DD;
    unsigned short* S2b  = S1b  + NND * DD;

    dim3 blk(256);
    dim3 rgrid(NND / 4);

    // K1: [G0b | E1b | S1pb] from x + degree/dedupe + wbuf tiles {1,2,5..9}
    mega_all<<<dim3(472), blk, 0, stream>>>(x, gcnW, poolW, mW, gcnB, poolB, mB,
                                            neigh, cnt, dinv, kept, wbuf,
                                            Gb, E1b, S1pb);
    // K2: H1b = propLN(G0b, resid=G0b); P1b = pool(E1b)
    prop_pool<<<rgrid, blk, 0, stream>>>(Gb, Gb, dinv, kept, neigh, cnt,
                                         gcnG, gcnBb, nullptr, DD, H1b, E1b, Pb);
    // K3: S1b = relu(S1pb + P1b@mW0R^T); G1b = H1b@gcnW1^T + b1
    gemm_step4<<<dim3(128, 2), blk, 0, stream>>>(Pb, H1b, wbuf, gcnB + DD,
                                                 S1pb, S1b, Gb);
    // K4: H2b = propLN(G1b, resid=H1b); P2b = pool(S1b)
    prop_pool<<<rgrid, blk, 0, stream>>>(Gb, H1b, dinv, kept, neigh, cnt,
                                         gcnG + DD, gcnBb + DD, nullptr, DD,
                                         H2b, S1b, Pb);
    // K5: S2b = LN(relu([S1b|P2b]@mW1^T + mB1) + S1b); G2b = H2b@gcnW2^T + b2
    gemm_step6<<<dim3(128, 2), blk, 0, stream>>>(S1b, Pb, H2b, wbuf,
                                                 mB + DD, gcnB + 2 * DD, sg, sb,
                                                 S2b, Gb);
    // K6: outL = propLN(G2b, resid=H2b) -> fp32 out; P3b = pool(S2b)
    prop_pool<<<rgrid, blk, 0, stream>>>(Gb, H2b, dinv, kept, neigh, cnt,
                                         gcnG + 2 * DD, gcnBb + 2 * DD,
                                         out, 2 * DD, nullptr, S2b, Pb);
    // K7: outR = LN(relu([S2b|P3b]@mW2^T + mB2) + S2b)
    gemm_final<<<dim3(128), blk, 0, stream>>>(S2b, Pb, wbuf, mB + 2 * DD,
                                              sg + DD, sb + DD, out);
}

// Round 13
// 129.081 us; speedup vs baseline: 1.0238x; 1.0013x over previous
//
#include <hip/hip_runtime.h>

#define NND 8192
#define KNBR 8
#define DD 128
#define EPSF 1e-5f
#define TSH 16384      // shorts per 128x128 bf16 tile (32 KB)
#define HSH 8192       // shorts per 64x128 half tile (16 KB)
#define XSTR 132       // LDS exchange row stride in floats

typedef __attribute__((ext_vector_type(8))) short bf16x8;
typedef __attribute__((ext_vector_type(4))) float f32x4;

__device__ __forceinline__ unsigned short f2bf(float f) {
    unsigned u = __float_as_uint(f);
    u += 0x7FFF + ((u >> 16) & 1);   // round-to-nearest-even
    return (unsigned short)(u >> 16);
}

__device__ __forceinline__ float bf_lo(unsigned u) { return __uint_as_float(u << 16); }
__device__ __forceinline__ float bf_hi(unsigned u) { return __uint_as_float(u & 0xFFFF0000u); }
__device__ __forceinline__ float bfs(unsigned short u) {
    return __uint_as_float((unsigned)u << 16);
}

__device__ __forceinline__ bf16x8 cvt8(const float* __restrict__ p) {
    float4 lo = *(const float4*)p;
    float4 hi = *(const float4*)(p + 4);
    bf16x8 r;
    r[0] = f2bf(lo.x); r[1] = f2bf(lo.y); r[2] = f2bf(lo.z); r[3] = f2bf(lo.w);
    r[4] = f2bf(hi.x); r[5] = f2bf(hi.y); r[6] = f2bf(hi.z); r[7] = f2bf(hi.w);
    return r;
}

// ---- async weight staging from pre-swizzled wbuf (linear DMA) ----
__device__ __forceinline__ void gload_lds16(const unsigned short* g, unsigned short* l) {
    __builtin_amdgcn_global_load_lds(
        (const __attribute__((address_space(1))) unsigned int*)(g),
        (__attribute__((address_space(3))) unsigned int*)(l), 16, 0, 0);
}

__device__ __forceinline__ void stage1(unsigned short* sh, const unsigned short* wb, int tid) {
    int lane = tid & 63, w = tid >> 6;
#pragma unroll
    for (int r = 0; r < 8; ++r) {
        int blk = (r * 4 + w) * 512;          // shorts, wave-uniform
        gload_lds16(wb + blk + lane * 8, sh + blk);
    }
}

// half tile (64 out-cols x 128 K = 16 KB)
__device__ __forceinline__ void stage_half(unsigned short* sh, const unsigned short* wb, int tid) {
    int lane = tid & 63, w = tid >> 6;
#pragma unroll
    for (int r = 0; r < 4; ++r) {
        int blk = (r * 4 + w) * 512;
        gload_lds16(wb + blk + lane * 8, sh + blk);
    }
}

// ---- in-kernel fp32->bf16 swizzled staging of a 64-row half tile ----
// Local row r (0..63) = W row rowOff+r; chunk ch stored at ch^(r&7).
__device__ __forceinline__ void stage_cvt_sw_h(unsigned short* sh, const float* __restrict__ W,
                                               int wstr, int rowOff, int tid) {
    int r = tid >> 2, qtr = tid & 3;
    const float* src = W + (size_t)(rowOff + r) * wstr;
#pragma unroll
    for (int i = 0; i < 4; ++i) {
        int ch = qtr * 4 + i;
        *(bf16x8*)(sh + r * 128 + ((ch ^ (r & 7)) << 3)) = cvt8(src + ch * 8);
    }
}

// ---- fragment loaders ----
__device__ __forceinline__ void load_af(bf16x8* af, const unsigned short* __restrict__ A,
                                        int rowBase, int lane) {
    int idx = lane & 15, q = lane >> 4;
    const unsigned short* Ar = A + (size_t)(rowBase + idx) * DD;
#pragma unroll
    for (int s = 0; s < 4; ++s) af[s] = *(const bf16x8*)(Ar + s * 32 + q * 8);
}

__device__ __forceinline__ void load_af_f32(bf16x8* af, const float* __restrict__ A,
                                            int rowBase, int lane) {
    int idx = lane & 15, q = lane >> 4;
    const float* Ar = A + (size_t)(rowBase + idx) * DD;
#pragma unroll
    for (int s = 0; s < 4; ++s) af[s] = cvt8(Ar + s * 32 + q * 8);
}

// ---- MFMA over swizzled LDS tiles (row&7 == idx&7 keys the unswizzle) ----
__device__ __forceinline__ void mma_sw(const bf16x8* af, const unsigned short* shB,
                                       int lane, f32x4* acc) {
    int idx = lane & 15, q = lane >> 4, k7 = idx & 7;
#pragma unroll
    for (int s = 0; s < 4; ++s)
#pragma unroll
        for (int ct = 0; ct < 8; ++ct) {
            int ch = (4 * s + q) ^ k7;
            bf16x8 bf = *(const bf16x8*)(shB + (ct * 16 + idx) * 128 + ch * 8);
            acc[ct] = __builtin_amdgcn_mfma_f32_16x16x32_bf16(af[s], bf, acc[ct], 0, 0, 0);
        }
}

__device__ __forceinline__ void mma_sw4(const bf16x8* af, const unsigned short* shB,
                                        int lane, f32x4* acc) {
    int idx = lane & 15, q = lane >> 4, k7 = idx & 7;
#pragma unroll
    for (int s = 0; s < 4; ++s)
#pragma unroll
        for (int ct = 0; ct < 4; ++ct) {
            int ch = (4 * s + q) ^ k7;
            bf16x8 bf = *(const bf16x8*)(shB + (ct * 16 + idx) * 128 + ch * 8);
            acc[ct] = __builtin_amdgcn_mfma_f32_16x16x32_bf16(af[s], bf, acc[ct], 0, 0, 0);
        }
}

// bf16 store, half-width (4 col-tiles) at colBase; optional relu
__device__ __forceinline__ void store_h_b16(unsigned short* __restrict__ out,
        int rowBase, int colBase, int lane, const f32x4* acc,
        const float* __restrict__ bias, bool relu) {
    int idx = lane & 15, q = lane >> 4;
#pragma unroll
    for (int ct = 0; ct < 4; ++ct) {
        float b = bias[colBase + ct * 16 + idx];
#pragma unroll
        for (int r = 0; r < 4; ++r) {
            float v = acc[ct][r] + b;
            if (relu) v = fmaxf(v, 0.f);
            out[(size_t)(rowBase + q * 4 + r) * DD + colBase + ct * 16 + idx] = f2bf(v);
        }
    }
}

// Fused LN epilogue, bf16 resid (full 128-col wave).
__device__ __forceinline__ void lnstore_fw_br(float* __restrict__ outF, int ostride, int oOff,
        const unsigned short* __restrict__ residB, int rowBase, int lane, f32x4* acc,
        const float* __restrict__ bias, const float* __restrict__ g,
        const float* __restrict__ bv, unsigned short* __restrict__ outB) {
    int idx = lane & 15, q = lane >> 4;
    float rsum[4] = {0.f, 0.f, 0.f, 0.f};
#pragma unroll
    for (int ct = 0; ct < 8; ++ct) {
        float b = bias[ct * 16 + idx];
#pragma unroll
        for (int r = 0; r < 4; ++r) {
            float t = fmaxf(acc[ct][r] + b, 0.f)
                    + bfs(residB[(size_t)(rowBase + q * 4 + r) * DD + ct * 16 + idx]);
            acc[ct][r] = t;
            rsum[r] += t;
        }
    }
#pragma unroll
    for (int r = 0; r < 4; ++r)
#pragma unroll
        for (int m = 1; m < 16; m <<= 1) rsum[r] += __shfl_xor(rsum[r], m, 64);
    float mu[4];
#pragma unroll
    for (int r = 0; r < 4; ++r) mu[r] = rsum[r] * (1.f / 128.f);
    float var[4] = {0.f, 0.f, 0.f, 0.f};
#pragma unroll
    for (int ct = 0; ct < 8; ++ct)
#pragma unroll
        for (int r = 0; r < 4; ++r) {
            float d = acc[ct][r] - mu[r];
            var[r] += d * d;
        }
#pragma unroll
    for (int r = 0; r < 4; ++r)
#pragma unroll
        for (int m = 1; m < 16; m <<= 1) var[r] += __shfl_xor(var[r], m, 64);
    float rs[4];
#pragma unroll
    for (int r = 0; r < 4; ++r) rs[r] = rsqrtf(var[r] * (1.f / 128.f) + EPSF);
#pragma unroll
    for (int ct = 0; ct < 8; ++ct) {
        float gg = g[ct * 16 + idx], bb = bv[ct * 16 + idx];
#pragma unroll
        for (int r = 0; r < 4; ++r) {
            float o = (acc[ct][r] - mu[r]) * rs[r] * gg + bb;
            size_t row = (size_t)(rowBase + q * 4 + r);
            if (outF) outF[row * ostride + oOff + ct * 16 + idx] = o;
            if (outB) outB[row * DD + ct * 16 + idx] = f2bf(o);
        }
    }
}

// ---- row-wise helpers ----
__device__ __forceinline__ float wave_sum(float s) {
#pragma unroll
    for (int m = 1; m < 64; m <<= 1) s += __shfl_xor(s, m, 64);
    return s;
}

// Merged prop+pool for one row: metadata once, all 17 gathers in flight.
__device__ __forceinline__ void prop_pool_row(int row, int lane,
        const unsigned short* __restrict__ nxtB, const unsigned short* __restrict__ residB,
        const unsigned short* __restrict__ enc,
        const float* __restrict__ dinv, const int* __restrict__ kept,
        const int* __restrict__ neigh, const int* __restrict__ cnt,
        const float* __restrict__ g, const float* __restrict__ b,
        float* __restrict__ outF, int oStride,
        unsigned short* __restrict__ outB, unsigned short* __restrict__ P) {
    const unsigned* nxt2 = (const unsigned*)nxtB;
    const unsigned* e32  = (const unsigned*)enc;
    int nb[KNBR];
#pragma unroll
    for (int j = 0; j < KNBR; ++j) nb[j] = neigh[row * KNBR + j];
    int km = kept[row];
    int c  = cnt[row];
    float di = dinv[row];
    int idxs[KNBR]; float wj[KNBR];
#pragma unroll
    for (int j = 0; j < KNBR; ++j) {
        bool k = (km >> j) & 1;
        idxs[j] = k ? nb[j] : row;
        wj[j] = k ? dinv[nb[j]] : 0.f;
    }
    unsigned vv[KNBR], pv[KNBR];
#pragma unroll
    for (int j = 0; j < KNBR; ++j) vv[j] = nxt2[(size_t)idxs[j] * 64 + lane];
#pragma unroll
    for (int j = 0; j < KNBR; ++j) {
        int src = (j < c) ? nb[j] : row;
        pv[j] = e32[(size_t)src * 64 + lane];
    }
    unsigned su = nxt2[(size_t)row * 64 + lane];
    unsigned ru = ((const unsigned*)residB)[(size_t)row * 64 + lane];
    float ax = di * bf_lo(su), ay = di * bf_hi(su);
#pragma unroll
    for (int j = 0; j < KNBR; ++j) {
        ax = fmaf(wj[j], bf_lo(vv[j]), ax);
        ay = fmaf(wj[j], bf_hi(vv[j]), ay);
    }
    float vx = fmaxf(di * ax, 0.f) + bf_lo(ru);
    float vy = fmaxf(di * ay, 0.f) + bf_hi(ru);
    float mu = wave_sum(vx + vy) * (1.f / 128.f);
    float dx = vx - mu, dy = vy - mu;
    float var = wave_sum(dx * dx + dy * dy) * (1.f / 128.f);
    float rs = rsqrtf(var + EPSF);
    float2 gg = ((const float2*)g)[lane];
    float2 bb = ((const float2*)b)[lane];
    float ox = dx * rs * gg.x + bb.x;
    float oy = dy * rs * gg.y + bb.y;
    if (outF) {
        float2 o; o.x = ox; o.y = oy;
        *reinterpret_cast<float2*>(outF + (size_t)row * oStride + lane * 2) = o;
    }
    if (outB) {
        unsigned pk = (unsigned)f2bf(ox) | ((unsigned)f2bf(oy) << 16);
        *(unsigned*)(outB + (size_t)row * DD + lane * 2) = pk;
    }
    float px = -1e30f, py = -1e30f;
#pragma unroll
    for (int j = 0; j < KNBR; ++j) {
        if (j < c) {
            px = fmaxf(px, bf_lo(pv[j]));
            py = fmaxf(py, bf_hi(pv[j]));
        }
    }
    unsigned o = 0u;
    if (c > 0)
        o = (__float_as_uint(px) >> 16) | (__float_as_uint(py) & 0xFFFF0000u);
    ((unsigned*)P)[(size_t)row * 64 + lane] = o;
}

// ---------------------------------------------------------------------------
// K1 mega_all: grid(856).
//   bid<768 : col-split GEMM from fp32 x. grp=bid/256, sub=bid%256,
//             bx=sub>>1, colHalf=sub&1. Each wave: 16 rows x 64 cols.
//   768..799: degree/dedupe
//   800..855: fp32->bf16 pre-swizzled wbuf tiles {1,2,5,6,7,8,9}
// ---------------------------------------------------------------------------
__global__ __launch_bounds__(256)
void mega_all(const float* __restrict__ x,
              const float* __restrict__ gcnW, const float* __restrict__ poolW,
              const float* __restrict__ mW,
              const float* __restrict__ gB0, const float* __restrict__ pB,
              const float* __restrict__ mB0,
              const int* __restrict__ neigh, const int* __restrict__ cnt,
              float* __restrict__ dinv, int* __restrict__ kept,
              unsigned short* __restrict__ wbuf,
              unsigned short* __restrict__ Gb, unsigned short* __restrict__ E1b,
              unsigned short* __restrict__ S1pb) {
    __shared__ __align__(16) unsigned short shB[HSH];
    const int bid = blockIdx.x, tid = threadIdx.x;
    const int lane = tid & 63, w = tid >> 6;

    if (bid < 768) {
        int grp = bid >> 8, sub = bid & 255;
        int bx = sub >> 1, colHalf = sub & 1, colBase = colHalf * 64;
        const float* W; int str;
        if (grp == 0)      { W = gcnW;  str = 128; }
        else if (grp == 1) { W = poolW; str = 128; }
        else               { W = mW;    str = 256; }
        stage_cvt_sw_h(shB, W, str, colBase, tid);
        int rowBase = (bx * 4 + w) * 16;
        bf16x8 af[4];
        load_af_f32(af, x, rowBase, lane);
        __syncthreads();
        f32x4 acc[4];
#pragma unroll
        for (int i = 0; i < 4; ++i) acc[i] = (f32x4){0.f, 0.f, 0.f, 0.f};
        mma_sw4(af, shB, lane, acc);
        if (grp == 0)      store_h_b16(Gb, rowBase, colBase, lane, acc, gB0, false);
        else if (grp == 1) store_h_b16(E1b, rowBase, colBase, lane, acc, pB, true);
        else               store_h_b16(S1pb, rowBase, colBase, lane, acc, mB0, false);
    } else if (bid < 800) {
        int i = (bid - 768) * 256 + tid;
        int c = cnt[i];
        int nb[KNBR];
#pragma unroll
        for (int j = 0; j < KNBR; ++j) nb[j] = neigh[i * KNBR + j];
        int mask = 0, deg = 1;
#pragma unroll
        for (int j = 0; j < KNBR; ++j) {
            if (j < c) {
                int v = nb[j];
                bool dup = (v == i);
                for (int jj = 0; jj < j; ++jj)
                    if (nb[jj] == v) { dup = true; }
                if (!dup) { mask |= (1 << j); deg++; }
            }
        }
        dinv[i] = rsqrtf((float)deg);
        kept[i] = mask;
    } else {
        int cid = (bid - 800) * 256 + tid;    // 0..14335
        int u = cid >> 11, c2 = cid & 2047, row = c2 >> 4, ch = c2 & 15;
        const float* base; int str; int t;
        if (u == 0)      { t = 1; base = gcnW + 16384;       str = 128; }
        else if (u == 1) { t = 2; base = gcnW + 32768;       str = 128; }
        else if (u == 2) { t = 5; base = mW + 128;           str = 256; }
        else if (u == 3) { t = 6; base = mW + 32768;         str = 256; }
        else if (u == 4) { t = 7; base = mW + 32768 + 128;   str = 256; }
        else if (u == 5) { t = 8; base = mW + 65536;         str = 256; }
        else             { t = 9; base = mW + 65536 + 128;   str = 256; }
        bf16x8 v = cvt8(base + (size_t)row * str + ch * 8);
        *(bf16x8*)(wbuf + t * TSH + row * 128 + ((ch ^ (row & 7)) << 3)) = v;
    }
}

// prop_pool: grid(2048). 1 merged prop+pool row per wave; 17 gathers in flight.
__global__ __launch_bounds__(256)
void prop_pool(const unsigned short* __restrict__ nxtB,
               const unsigned short* __restrict__ residB,
               const float* __restrict__ dinv, const int* __restrict__ kept,
               const int* __restrict__ neigh, const int* __restrict__ cnt,
               const float* __restrict__ g, const float* __restrict__ b,
               float* __restrict__ outF, int oStride,
               unsigned short* __restrict__ outB,
               const unsigned short* __restrict__ enc,
               unsigned short* __restrict__ P) {
    int row = blockIdx.x * 4 + (threadIdx.x >> 6);
    int lane = threadIdx.x & 63;
    prop_pool_row(row, lane, nxtB, residB, enc, dinv, kept, neigh, cnt,
                  g, b, outF, oStride, outB, P);
}

// step4: grid (256, 2). Col-split: bx=blockIdx.x>>1, colHalf=blockIdx.x&1.
//  y0: S1b = bf16(relu(S1pb + Pb@mW0R^T))   (pointwise)
//  y1: G1b = bf16(H1b@gcnW1^T + gB1)
__global__ __launch_bounds__(256)
void gemm_step4(const unsigned short* __restrict__ Pb, const unsigned short* __restrict__ H1b,
                const unsigned short* __restrict__ wbuf, const float* __restrict__ gB1,
                const unsigned short* __restrict__ S1pb, unsigned short* __restrict__ S1b,
                unsigned short* __restrict__ Gb) {
    __shared__ __align__(16) unsigned short shB[HSH];
    const int tid = threadIdx.x, lane = tid & 63, w = tid >> 6;
    const int bx = (int)blockIdx.x >> 1, colHalf = blockIdx.x & 1;
    const int colBase = colHalf * 64;
    const int rowBase = (bx * 4 + w) * 16;
    f32x4 acc[4];
#pragma unroll
    for (int i = 0; i < 4; ++i) acc[i] = (f32x4){0.f, 0.f, 0.f, 0.f};
    bf16x8 af[4];
    if (blockIdx.y == 0) {
        stage_half(shB, wbuf + 5 * TSH + colHalf * HSH, tid);   // mW0R half
        load_af(af, Pb, rowBase, lane);
        __syncthreads();
        mma_sw4(af, shB, lane, acc);
        int idx = lane & 15, q = lane >> 4;
#pragma unroll
        for (int ct = 0; ct < 4; ++ct)
#pragma unroll
            for (int r = 0; r < 4; ++r) {
                size_t o = (size_t)(rowBase + q * 4 + r) * DD + colBase + ct * 16 + idx;
                float v = fmaxf(bfs(S1pb[o]) + acc[ct][r], 0.f);
                S1b[o] = f2bf(v);
            }
    } else {
        stage_half(shB, wbuf + 1 * TSH + colHalf * HSH, tid);   // gcnW1 half
        load_af(af, H1b, rowBase, lane);
        __syncthreads();
        mma_sw4(af, shB, lane, acc);
        store_h_b16(Gb, rowBase, colBase, lane, acc, gB1, false);
    }
}

// step6: grid (384).
//  bid<128 : y0 full-width: S2b = bf16(LN(relu([S1b|Pb]@mW1^T + mB1) + S1b))
//  bid>=128: y1 col-split:  G2b = bf16(H2b@gcnW2^T + gB2)
__global__ __launch_bounds__(256)
void gemm_step6(const unsigned short* __restrict__ S1b, const unsigned short* __restrict__ Pb,
                const unsigned short* __restrict__ H2b,
                const unsigned short* __restrict__ wbuf,
                const float* __restrict__ mB1, const float* __restrict__ gB2,
                const float* __restrict__ sg, const float* __restrict__ sb,
                unsigned short* __restrict__ S2b, unsigned short* __restrict__ Gb) {
    __shared__ __align__(16) unsigned short shB[2 * TSH];
    const int bid = blockIdx.x, tid = threadIdx.x, lane = tid & 63, w = tid >> 6;
    if (bid < 128) {
        const int rowBase = (bid * 4 + w) * 16;
        f32x4 acc[8];
#pragma unroll
        for (int i = 0; i < 8; ++i) acc[i] = (f32x4){0.f, 0.f, 0.f, 0.f};
        stage1(shB, wbuf + 6 * TSH, tid);        // mW1L
        stage1(shB + TSH, wbuf + 7 * TSH, tid);  // mW1R
        bf16x8 af1[4], af2[4];
        load_af(af1, S1b, rowBase, lane);
        load_af(af2, Pb, rowBase, lane);
        __syncthreads();
        mma_sw(af1, shB, lane, acc);
        mma_sw(af2, shB + TSH, lane, acc);
        lnstore_fw_br(nullptr, DD, 0, S1b, rowBase, lane, acc, mB1, sg, sb, S2b);
    } else {
        int sub = bid - 128;
        int bx = sub >> 1, colHalf = sub & 1, colBase = colHalf * 64;
        const int rowBase = (bx * 4 + w) * 16;
        f32x4 acc[4];
#pragma unroll
        for (int i = 0; i < 4; ++i) acc[i] = (f32x4){0.f, 0.f, 0.f, 0.f};
        stage_half(shB, wbuf + 2 * TSH + colHalf * HSH, tid);   // gcnW2 half
        bf16x8 af[4];
        load_af(af, H2b, rowBase, lane);
        __syncthreads();
        mma_sw4(af, shB, lane, acc);
        store_h_b16(Gb, rowBase, colBase, lane, acc, gB2, false);
    }
}

// final: grid (256). K-split (R3 pattern): wave pairs — unit0: S2b@mW2L,
// unit1: Pb@mW2R; combine via padded LDS exchange; LN on unit0.
__global__ __launch_bounds__(256)
void gemm_final(const unsigned short* __restrict__ S2b, const unsigned short* __restrict__ Pb,
                const unsigned short* __restrict__ wbuf,
                const float* __restrict__ mB2,
                const float* __restrict__ sg2, const float* __restrict__ sb2,
                float* __restrict__ out) {
    __shared__ __align__(16) unsigned short shB[2 * TSH];
    __shared__ float xch[32 * XSTR];
    const int tid = threadIdx.x, lane = tid & 63, w = tid >> 6;
    stage1(shB, wbuf + 8 * TSH, tid);        // mW2L
    stage1(shB + TSH, wbuf + 9 * TSH, tid);  // mW2R
    const int rt = w & 1, unit = w >> 1;
    const int rowBase = (int)blockIdx.x * 32 + rt * 16;
    bf16x8 af[4];
    load_af(af, unit ? Pb : S2b, rowBase, lane);
    __syncthreads();
    f32x4 acc[8];
#pragma unroll
    for (int i = 0; i < 8; ++i) acc[i] = (f32x4){0.f, 0.f, 0.f, 0.f};
    mma_sw(af, shB + unit * TSH, lane, acc);
    int idx = lane & 15, q = lane >> 4;
    if (unit) {
#pragma unroll
        for (int ct = 0; ct < 8; ++ct)
#pragma unroll
            for (int r = 0; r < 4; ++r)
                xch[(rt * 16 + q * 4 + r) * XSTR + ct * 16 + idx] = acc[ct][r];
    }
    __syncthreads();
    if (!unit) {
#pragma unroll
        for (int ct = 0; ct < 8; ++ct)
#pragma unroll
            for (int r = 0; r < 4; ++r)
                acc[ct][r] += xch[(rt * 16 + q * 4 + r) * XSTR + ct * 16 + idx];
        lnstore_fw_br(out, 2 * DD, DD, S2b, rowBase, lane, acc, mB2, sg2, sb2, nullptr);
    }
}

extern "C" void kernel_launch(void* const* d_in, const int* in_sizes, int n_in,
                              void* d_out, int out_size, void* d_ws, size_t ws_size,
                              hipStream_t stream) {
    (void)in_sizes; (void)n_in; (void)out_size; (void)ws_size;
    const float* x      = (const float*)d_in[0];
    const int*   neigh  = (const int*)d_in[1];
    const int*   cnt    = (const int*)d_in[2];
    const float* gcnW   = (const float*)d_in[3];
    const float* gcnB   = (const float*)d_in[4];
    const float* gcnG   = (const float*)d_in[5];
    const float* gcnBb  = (const float*)d_in[6];
    const float* poolW  = (const float*)d_in[7];
    const float* poolB  = (const float*)d_in[8];
    const float* mW     = (const float*)d_in[9];
    const float* mB     = (const float*)d_in[10];
    const float* sg     = (const float*)d_in[11];
    const float* sb     = (const float*)d_in[12];
    float* out = (float*)d_out;

    char* ws = (char*)d_ws;
    float* dinv = (float*)ws;                                 // 32 KB
    int*   kept = (int*)(ws + 32 * 1024);                     // 32 KB
    unsigned short* wbuf = (unsigned short*)(ws + 64 * 1024); // 320 KB (10 tiles)
    unsigned short* Gb   = (unsigned short*)(ws + 448 * 1024);// bf16: 2 MB each
    unsigned short* E1b  = Gb   + NND * DD;
    unsigned short* S1pb = E1b  + NND * DD;
    unsigned short* Pb   = S1pb + NND * DD;
    unsigned short* H1b  = Pb   + NND * DD;
    unsigned short* H2b  = H1b  + NND * DD;
    unsigned short* S1b  = H2b  + NND * DD;
    unsigned short* S2b  = S1b  + NND * DD;

    dim3 blk(256);
    dim3 rgrid(NND / 4);

    // K1: [G0b | E1b | S1pb] from x + degree/dedupe + wbuf tiles {1,2,5..9}
    mega_all<<<dim3(856), blk, 0, stream>>>(x, gcnW, poolW, mW, gcnB, poolB, mB,
                                            neigh, cnt, dinv, kept, wbuf,
                                            Gb, E1b, S1pb);
    // K2: H1b = propLN(G0b, resid=G0b); P1b = pool(E1b)
    prop_pool<<<rgrid, blk, 0, stream>>>(Gb, Gb, dinv, kept, neigh, cnt,
                                         gcnG, gcnBb, nullptr, DD, H1b, E1b, Pb);
    // K3: S1b = relu(S1pb + P1b@mW0R^T); G1b = H1b@gcnW1^T + b1
    gemm_step4<<<dim3(256, 2), blk, 0, stream>>>(Pb, H1b, wbuf, gcnB + DD,
                                                 S1pb, S1b, Gb);
    // K4: H2b = propLN(G1b, resid=H1b); P2b = pool(S1b)
    prop_pool<<<rgrid, blk, 0, stream>>>(Gb, H1b, dinv, kept, neigh, cnt,
                                         gcnG + DD, gcnBb + DD, nullptr, DD,
                                         H2b, S1b, Pb);
    // K5: S2b = LN(relu([S1b|P2b]@mW1^T + mB1) + S1b); G2b = H2b@gcnW2^T + b2
    gemm_step6<<<dim3(384), blk, 0, stream>>>(S1b, Pb, H2b, wbuf,
                                              mB + DD, gcnB + 2 * DD, sg, sb,
                                              S2b, Gb);
    // K6: outL = propLN(G2b, resid=H2b) -> fp32 out; P3b = pool(S2b)
    prop_pool<<<rgrid, blk, 0, stream>>>(Gb, H2b, dinv, kept, neigh, cnt,
                                         gcnG + 2 * DD, gcnBb + 2 * DD,
                                         out, 2 * DD, nullptr, S2b, Pb);
    // K7: outR = LN(relu([S2b|P3b]@mW2^T + mB2) + S2b)
    gemm_final<<<dim3(256), blk, 0, stream>>>(S2b, Pb, wbuf, mB + 2 * DD,
                                              sg + DD, sb + DD, out);
}